// Round 1
// baseline (232.401 us; speedup 1.0000x reference)
//
#include <hip/hip_runtime.h>
#include <hip/hip_bf16.h>

// ---------- types ----------
typedef __attribute__((ext_vector_type(8))) short bf16x8;   // 8 bf16 in 4 VGPRs
typedef __attribute__((ext_vector_type(4))) float f32x4;    // MFMA accumulator
typedef __attribute__((ext_vector_type(8))) unsigned short u16x8;

static __device__ __forceinline__ unsigned short f2bf(float f) {
    // fp32 -> bf16 round-to-nearest-even (inputs are finite)
    union { float f; unsigned int u; } v; v.f = f;
    unsigned int u = v.u;
    u += 0x7FFFu + ((u >> 16) & 1u);
    return (unsigned short)(u >> 16);
}

// ---------- K1a: W fp32[256][512] -> bf16 ----------
__global__ void __launch_bounds__(256) convert_w(const float* __restrict__ W,
                                                 unsigned short* __restrict__ Wbf) {
    int i = (blockIdx.x * 256 + threadIdx.x) * 4;   // 131072 elems, grid=128
    float4 v = *(const float4*)(W + i);
    ushort4 o;
    o.x = f2bf(v.x); o.y = f2bf(v.y); o.z = f2bf(v.z); o.w = f2bf(v.w);
    *(ushort4*)(Wbf + i) = o;
}

// ---------- K1b: x_vit fp32[8][512][1024] -> Xt bf16[8][1024][512] (k-contiguous) ----------
__global__ void __launch_bounds__(256) transpose_xvit(const float* __restrict__ X,
                                                      unsigned short* __restrict__ Xt) {
    __shared__ unsigned short ls[64][65];   // [p][c], padded
    int b  = blockIdx.z;
    int c0 = blockIdx.y * 64;
    int p0 = blockIdx.x * 64;
    int t  = threadIdx.x;

    const float* src = X + ((size_t)b * 512 + c0) * 1024 + p0;
    int cc = t >> 4;          // 0..15
    int p4 = (t & 15) << 2;   // 0..60
    #pragma unroll
    for (int i = 0; i < 4; ++i) {
        int c = cc + i * 16;
        float4 v = *(const float4*)(src + (size_t)c * 1024 + p4);
        ls[p4 + 0][c] = f2bf(v.x);
        ls[p4 + 1][c] = f2bf(v.y);
        ls[p4 + 2][c] = f2bf(v.z);
        ls[p4 + 3][c] = f2bf(v.w);
    }
    __syncthreads();

    unsigned short* dst = Xt + ((size_t)b * 1024 + p0) * 512 + c0;
    int pp  = t >> 2;         // 0..63
    int c16 = (t & 3) << 4;   // 0,16,32,48
    u16x8 w0, w1;
    #pragma unroll
    for (int j = 0; j < 8; ++j) { w0[j] = ls[pp][c16 + j]; w1[j] = ls[pp][c16 + 8 + j]; }
    *(u16x8*)(dst + (size_t)pp * 512 + c16)     = w0;
    *(u16x8*)(dst + (size_t)pp * 512 + c16 + 8) = w1;
}

// ---------- K2: V[b][m][n] = sum_k Wbf[m][k]*Xt[b][n][k] + bias[m] ----------
// M=256, N=1024 (per batch), K=512. 64x64 tile per block, 4 waves in 2x2,
// each wave 2x2 of 16x16x32 bf16 MFMAs.
__global__ void __launch_bounds__(256) gemm_bf16(const unsigned short* __restrict__ Wbf,
                                                 const unsigned short* __restrict__ Xt,
                                                 const float* __restrict__ bias,
                                                 float* __restrict__ V) {
    __shared__ __align__(16) unsigned short As[64 * 32];  // [m][k]
    __shared__ __align__(16) unsigned short Bs[64 * 32];  // [n][k]

    int b  = blockIdx.z;
    int m0 = blockIdx.y * 64;
    int n0 = blockIdx.x * 64;
    int t  = threadIdx.x;
    int wave = t >> 6;            // 0..3
    int lane = t & 63;
    int wm = (wave >> 1) * 32;    // wave m-offset within tile
    int wn = (wave & 1) * 32;     // wave n-offset
    int l15  = lane & 15;
    int quad = lane >> 4;

    // staging pointers: thread t loads 8 bf16 (16B); 4 threads per 64-row
    const unsigned short* Aglob = Wbf + (size_t)(m0 + (t >> 2)) * 512 + ((t & 3) << 3);
    const unsigned short* Bglob = Xt + ((size_t)b * 1024 + n0 + (t >> 2)) * 512 + ((t & 3) << 3);
    unsigned short* Asw = As + (t >> 2) * 32 + ((t & 3) << 3);
    unsigned short* Bsw = Bs + (t >> 2) * 32 + ((t & 3) << 3);

    f32x4 acc[2][2] = {};

    for (int k0 = 0; k0 < 512; k0 += 32) {
        *(u16x8*)Asw = *(const u16x8*)(Aglob + k0);
        *(u16x8*)Bsw = *(const u16x8*)(Bglob + k0);
        __syncthreads();

        // A[m=l15][k=quad*8+j], B[k=quad*8+j][n=l15] -- k-contiguous b128 reads
        bf16x8 a0 = *(const bf16x8*)(As + (wm + l15) * 32 + quad * 8);
        bf16x8 a1 = *(const bf16x8*)(As + (wm + 16 + l15) * 32 + quad * 8);
        bf16x8 b0 = *(const bf16x8*)(Bs + (wn + l15) * 32 + quad * 8);
        bf16x8 b1 = *(const bf16x8*)(Bs + (wn + 16 + l15) * 32 + quad * 8);

        acc[0][0] = __builtin_amdgcn_mfma_f32_16x16x32_bf16(a0, b0, acc[0][0], 0, 0, 0);
        acc[0][1] = __builtin_amdgcn_mfma_f32_16x16x32_bf16(a0, b1, acc[0][1], 0, 0, 0);
        acc[1][0] = __builtin_amdgcn_mfma_f32_16x16x32_bf16(a1, b0, acc[1][0], 0, 0, 0);
        acc[1][1] = __builtin_amdgcn_mfma_f32_16x16x32_bf16(a1, b1, acc[1][1], 0, 0, 0);
        __syncthreads();
    }

    // D mapping (verified): col = lane&15, row = quad*4 + reg
    #pragma unroll
    for (int mi = 0; mi < 2; ++mi)
        #pragma unroll
        for (int ni = 0; ni < 2; ++ni)
            #pragma unroll
            for (int r = 0; r < 4; ++r) {
                int gm = m0 + wm + mi * 16 + quad * 4 + r;
                int gn = n0 + wn + ni * 16 + l15;
                V[((size_t)b * 256 + gm) * 1024 + gn] = acc[mi][ni][r] + bias[gm];
            }
}

// ---------- K3: fused bilinear-upsample + per-pixel cosine ----------
__global__ void __launch_bounds__(256) fused_cos(const float* __restrict__ xcnn, // [8][256][128][128]
                                                 const float* __restrict__ V,    // [8][256][32][32]
                                                 float* __restrict__ out) {      // [8][1][128][128]
    int g  = blockIdx.x * 256 + threadIdx.x;
    int b  = g >> 14;
    int hw = g & 16383;
    int h  = hw >> 7;
    int w  = hw & 127;

    // half-pixel centers, scale 4, edge-clamped taps (== torch align_corners=False)
    float sy = (h + 0.5f) * 0.25f - 0.5f;
    float sx = (w + 0.5f) * 0.25f - 0.5f;
    float fy = floorf(sy), fx = floorf(sx);
    float dy = sy - fy,   dx = sx - fx;
    int y0 = max(0, min(31, (int)fy));
    int y1 = max(0, min(31, (int)fy + 1));
    int x0 = max(0, min(31, (int)fx));
    int x1 = max(0, min(31, (int)fx + 1));
    float w00 = (1.f - dy) * (1.f - dx);
    float w01 = (1.f - dy) * dx;
    float w10 = dy * (1.f - dx);
    float w11 = dy * dx;

    const float* xc = xcnn + (size_t)b * 256 * 16384 + hw;
    const float* vb = V + (size_t)b * 256 * 1024;
    int o00 = y0 * 32 + x0, o01 = y0 * 32 + x1;
    int o10 = y1 * 32 + x0, o11 = y1 * 32 + x1;

    float dot = 0.f, nx = 0.f, nv = 0.f;
    #pragma unroll 4
    for (int c = 0; c < 256; ++c) {
        float xv = xc[(size_t)c * 16384];
        const float* vc = vb + c * 1024;
        float v = w00 * vc[o00] + w01 * vc[o01] + w10 * vc[o10] + w11 * vc[o11];
        dot += xv * v;
        nx  += xv * xv;
        nv  += v * v;
    }
    out[g] = dot / (sqrtf(nx) * sqrtf(nv) + 1e-8f);
}

extern "C" void kernel_launch(void* const* d_in, const int* in_sizes, int n_in,
                              void* d_out, int out_size, void* d_ws, size_t ws_size,
                              hipStream_t stream) {
    const float* x_cnn = (const float*)d_in[0];  // [8][256][128][128]
    const float* x_vit = (const float*)d_in[1];  // [8][512][32][32]
    const float* W     = (const float*)d_in[2];  // [256][512]
    const float* bias  = (const float*)d_in[3];  // [256]
    float* out = (float*)d_out;                  // [8][1][128][128] fp32

    char* ws = (char*)d_ws;
    float*          V   = (float*)ws;                         // 8*256*1024 f32  = 8 MB
    unsigned short* Xt  = (unsigned short*)(ws + 8388608);    // 8*1024*512 bf16 = 8 MB
    unsigned short* Wbf = (unsigned short*)(ws + 16777216);   // 256*512 bf16    = 256 KB

    convert_w<<<128, 256, 0, stream>>>(W, Wbf);
    transpose_xvit<<<dim3(16, 8, 8), 256, 0, stream>>>(x_vit, Xt);
    gemm_bf16<<<dim3(16, 4, 8), 256, 0, stream>>>(Wbf, Xt, bias, V);
    fused_cos<<<512, 256, 0, stream>>>(x_cnn, V, out);
}

// Round 2
// 223.113 us; speedup vs baseline: 1.0416x; 1.0416x over previous
//
#include <hip/hip_runtime.h>
#include <hip/hip_bf16.h>

// ---------- types ----------
typedef __attribute__((ext_vector_type(8))) short bf16x8;   // 8 bf16 in 4 VGPRs
typedef __attribute__((ext_vector_type(4))) float f32x4;    // MFMA accumulator
typedef __attribute__((ext_vector_type(8))) unsigned short u16x8;
typedef __attribute__((ext_vector_type(4), aligned(4))) float f32x4u;  // dword-aligned vec load

static __device__ __forceinline__ unsigned short f2bf(float f) {
    union { float f; unsigned int u; } v; v.f = f;
    unsigned int u = v.u;
    u += 0x7FFFu + ((u >> 16) & 1u);
    return (unsigned short)(u >> 16);
}

// ---------- K1a: W fp32[256][512] -> bf16 ----------
__global__ void __launch_bounds__(256) convert_w(const float* __restrict__ W,
                                                 unsigned short* __restrict__ Wbf) {
    int i = (blockIdx.x * 256 + threadIdx.x) * 4;   // 131072 elems, grid=128
    float4 v = *(const float4*)(W + i);
    ushort4 o;
    o.x = f2bf(v.x); o.y = f2bf(v.y); o.z = f2bf(v.z); o.w = f2bf(v.w);
    *(ushort4*)(Wbf + i) = o;
}

// ---------- K1b: x_vit fp32[8][512][1024] -> Xt bf16[8][1024][512] ----------
__global__ void __launch_bounds__(256) transpose_xvit(const float* __restrict__ X,
                                                      unsigned short* __restrict__ Xt) {
    __shared__ unsigned short ls[64][65];   // [p][c], padded
    int b  = blockIdx.z;
    int c0 = blockIdx.y * 64;
    int p0 = blockIdx.x * 64;
    int t  = threadIdx.x;

    const float* src = X + ((size_t)b * 512 + c0) * 1024 + p0;
    int cc = t >> 4;          // 0..15
    int p4 = (t & 15) << 2;   // 0..60
    #pragma unroll
    for (int i = 0; i < 4; ++i) {
        int c = cc + i * 16;
        float4 v = *(const float4*)(src + (size_t)c * 1024 + p4);
        ls[p4 + 0][c] = f2bf(v.x);
        ls[p4 + 1][c] = f2bf(v.y);
        ls[p4 + 2][c] = f2bf(v.z);
        ls[p4 + 3][c] = f2bf(v.w);
    }
    __syncthreads();

    unsigned short* dst = Xt + ((size_t)b * 1024 + p0) * 512 + c0;
    int pp  = t >> 2;         // 0..63
    int c16 = (t & 3) << 4;   // 0,16,32,48
    u16x8 w0, w1;
    #pragma unroll
    for (int j = 0; j < 8; ++j) { w0[j] = ls[pp][c16 + j]; w1[j] = ls[pp][c16 + 8 + j]; }
    *(u16x8*)(dst + (size_t)pp * 512 + c16)     = w0;
    *(u16x8*)(dst + (size_t)pp * 512 + c16 + 8) = w1;
}

// ---------- K2: V[b][m][n] = sum_k Wbf[m][k]*Xt[b][n][k] + bias[m] ----------
__global__ void __launch_bounds__(256) gemm_bf16(const unsigned short* __restrict__ Wbf,
                                                 const unsigned short* __restrict__ Xt,
                                                 const float* __restrict__ bias,
                                                 float* __restrict__ V) {
    __shared__ __align__(16) unsigned short As[64 * 32];  // [m][k]
    __shared__ __align__(16) unsigned short Bs[64 * 32];  // [n][k]

    int b  = blockIdx.z;
    int m0 = blockIdx.y * 64;
    int n0 = blockIdx.x * 64;
    int t  = threadIdx.x;
    int wave = t >> 6;
    int lane = t & 63;
    int wm = (wave >> 1) * 32;
    int wn = (wave & 1) * 32;
    int l15  = lane & 15;
    int quad = lane >> 4;

    const unsigned short* Aglob = Wbf + (size_t)(m0 + (t >> 2)) * 512 + ((t & 3) << 3);
    const unsigned short* Bglob = Xt + ((size_t)b * 1024 + n0 + (t >> 2)) * 512 + ((t & 3) << 3);
    unsigned short* Asw = As + (t >> 2) * 32 + ((t & 3) << 3);
    unsigned short* Bsw = Bs + (t >> 2) * 32 + ((t & 3) << 3);

    f32x4 acc[2][2] = {};

    for (int k0 = 0; k0 < 512; k0 += 32) {
        *(u16x8*)Asw = *(const u16x8*)(Aglob + k0);
        *(u16x8*)Bsw = *(const u16x8*)(Bglob + k0);
        __syncthreads();

        bf16x8 a0 = *(const bf16x8*)(As + (wm + l15) * 32 + quad * 8);
        bf16x8 a1 = *(const bf16x8*)(As + (wm + 16 + l15) * 32 + quad * 8);
        bf16x8 b0 = *(const bf16x8*)(Bs + (wn + l15) * 32 + quad * 8);
        bf16x8 b1 = *(const bf16x8*)(Bs + (wn + 16 + l15) * 32 + quad * 8);

        acc[0][0] = __builtin_amdgcn_mfma_f32_16x16x32_bf16(a0, b0, acc[0][0], 0, 0, 0);
        acc[0][1] = __builtin_amdgcn_mfma_f32_16x16x32_bf16(a0, b1, acc[0][1], 0, 0, 0);
        acc[1][0] = __builtin_amdgcn_mfma_f32_16x16x32_bf16(a1, b0, acc[1][0], 0, 0, 0);
        acc[1][1] = __builtin_amdgcn_mfma_f32_16x16x32_bf16(a1, b1, acc[1][1], 0, 0, 0);
        __syncthreads();
    }

    #pragma unroll
    for (int mi = 0; mi < 2; ++mi)
        #pragma unroll
        for (int ni = 0; ni < 2; ++ni)
            #pragma unroll
            for (int r = 0; r < 4; ++r) {
                int gm = m0 + wm + mi * 16 + quad * 4 + r;
                int gn = n0 + wn + ni * 16 + l15;
                V[((size_t)b * 256 + gm) * 1024 + gn] = acc[mi][ni][r] + bias[gm];
            }
}

// ---------- K3: fused bilinear-upsample + per-pixel cosine (v2) ----------
// 1 block per (b, output row h). 256 threads = 32 w-quads x 8 channel-slices.
// Each thread: 4 consecutive w-pixels (float4 x-loads), 32 channels.
// V corners: 2 float4 loads/channel (top & bottom source rows, cols cb..cb+3),
// row-blended once, then per-pixel precomputed column weights (edge clamp folded).
__global__ void __launch_bounds__(256) fused_cos(const float* __restrict__ xcnn, // [8][256][128][128]
                                                 const float* __restrict__ V,    // [8][256][32][32]
                                                 float* __restrict__ out) {      // [8][1][128][128]
    __shared__ float red[8 * 385];   // [cs][ (q*4+px)*3 + j ], stride 385 breaks conflicts

    int bh = blockIdx.x;
    int b  = bh >> 7;
    int h  = bh & 127;
    int t  = threadIdx.x;
    int q  = t & 31;     // w-quad: pixels 4q..4q+3
    int cs = t >> 5;     // channel slice: channels cs*32..cs*32+31

    // ----- row interpolation (same for all 4 pixels of this thread) -----
    float sy = (h + 0.5f) * 0.25f - 0.5f;
    float fy = floorf(sy);
    float dy = sy - fy;
    int y0 = max(0, min(31, (int)fy));
    int y1 = max(0, min(31, (int)fy + 1));

    // ----- column weights per pixel, folded with edge clamp -----
    int cb = max(0, min(28, q - 1));      // float4 base col, covers all needed cols
    float a[4][4];
    #pragma unroll
    for (int px = 0; px < 4; ++px) {
        #pragma unroll
        for (int j = 0; j < 4; ++j) a[px][j] = 0.f;
        int w = q * 4 + px;
        float sx = (w + 0.5f) * 0.25f - 0.5f;
        float fx = floorf(sx);
        float dx = sx - fx;
        int x0 = max(0, min(31, (int)fx));
        int x1 = max(0, min(31, (int)fx + 1));
        a[px][x0 - cb] += 1.f - dx;
        a[px][x1 - cb] += dx;
    }

    const float* xp = xcnn + ((size_t)(b * 256 + cs * 32) * 16384) + h * 128 + q * 4;
    const float* vt = V + ((size_t)(b * 256 + cs * 32) * 1024) + y0 * 32 + cb;
    const float* vb = V + ((size_t)(b * 256 + cs * 32) * 1024) + y1 * 32 + cb;
    float ry = dy, ry0 = 1.f - dy;

    float dot[4] = {0.f, 0.f, 0.f, 0.f};
    float nx [4] = {0.f, 0.f, 0.f, 0.f};
    float nv [4] = {0.f, 0.f, 0.f, 0.f};

    #pragma unroll 8
    for (int c = 0; c < 32; ++c) {
        float4  xv  = *(const float4*)(xp + (size_t)c * 16384);
        f32x4u  top = *(const f32x4u*)(vt + (size_t)c * 1024);
        f32x4u  bot = *(const f32x4u*)(vb + (size_t)c * 1024);
        float bl0 = ry0 * top[0] + ry * bot[0];
        float bl1 = ry0 * top[1] + ry * bot[1];
        float bl2 = ry0 * top[2] + ry * bot[2];
        float bl3 = ry0 * top[3] + ry * bot[3];
        float xs[4] = {xv.x, xv.y, xv.z, xv.w};
        #pragma unroll
        for (int px = 0; px < 4; ++px) {
            float v = a[px][0] * bl0 + a[px][1] * bl1 + a[px][2] * bl2 + a[px][3] * bl3;
            dot[px] += xs[px] * v;
            nx [px] += xs[px] * xs[px];
            nv [px] += v * v;
        }
    }

    // ----- cross-slice reduction in LDS -----
    float* my = red + cs * 385;
    #pragma unroll
    for (int px = 0; px < 4; ++px) {
        int o = (q * 4 + px) * 3;
        my[o + 0] = dot[px];
        my[o + 1] = nx[px];
        my[o + 2] = nv[px];
    }
    __syncthreads();

    if (t < 128) {                 // one thread per output pixel of this row
        int px = t & 3;
        int q2 = t >> 2;
        int o  = (q2 * 4 + px) * 3;
        float d = 0.f, sx2 = 0.f, sv2 = 0.f;
        #pragma unroll
        for (int s = 0; s < 8; ++s) {
            d   += red[s * 385 + o + 0];
            sx2 += red[s * 385 + o + 1];
            sv2 += red[s * 385 + o + 2];
        }
        out[(size_t)b * 16384 + h * 128 + q2 * 4 + px] =
            d / (sqrtf(sx2) * sqrtf(sv2) + 1e-8f);
    }
}

extern "C" void kernel_launch(void* const* d_in, const int* in_sizes, int n_in,
                              void* d_out, int out_size, void* d_ws, size_t ws_size,
                              hipStream_t stream) {
    const float* x_cnn = (const float*)d_in[0];  // [8][256][128][128]
    const float* x_vit = (const float*)d_in[1];  // [8][512][32][32]
    const float* W     = (const float*)d_in[2];  // [256][512]
    const float* bias  = (const float*)d_in[3];  // [256]
    float* out = (float*)d_out;                  // [8][1][128][128] fp32

    char* ws = (char*)d_ws;
    float*          V   = (float*)ws;                         // 8*256*1024 f32  = 8 MB
    unsigned short* Xt  = (unsigned short*)(ws + 8388608);    // 8*1024*512 bf16 = 8 MB
    unsigned short* Wbf = (unsigned short*)(ws + 16777216);   // 256*512 bf16    = 256 KB

    convert_w<<<128, 256, 0, stream>>>(W, Wbf);
    transpose_xvit<<<dim3(16, 8, 8), 256, 0, stream>>>(x_vit, Xt);
    gemm_bf16<<<dim3(16, 4, 8), 256, 0, stream>>>(Wbf, Xt, bias, V);
    fused_cos<<<1024, 256, 0, stream>>>(x_cnn, V, out);
}